// Round 5
// baseline (576.796 us; speedup 1.0000x reference)
//
#include <hip/hip_runtime.h>
#include <hip/hip_bf16.h>

#define NN 100000
#define EE 1600000
#define ET (EE + NN)
#define NBK 391           // dst buckets of 256 nodes: ceil(100000/256)
#define NBLK 208          // binning blocks: ceil(ET/8192)
#define STAGE_CAP 4096    // LDS pair stage per bucket (mean ~4350; overflow re-reads L2)
#define AGG_NS 72         // agg LDS node stride (bf16): 144B, 16B-aligned, bank-spread
#define AGG_HS 1160       // agg LDS head stride (bf16): 16*72+8

typedef unsigned short ushort_t;
typedef short short8 __attribute__((ext_vector_type(8)));
typedef float f32x4 __attribute__((ext_vector_type(4)));

static __device__ __forceinline__ float b2f(unsigned short u) {
    return __uint_as_float(((unsigned int)u) << 16);
}
static __device__ __forceinline__ unsigned short f2b(float f) {
    unsigned int x = __float_as_uint(f);
    return (unsigned short)((x + 0x7fffu + ((x >> 16) & 1u)) >> 16);
}

// ---------------- GEMM1 body (shared by kfuse1/kfuse2): h1[row0..row0+64) = x @ W1
static __device__ void gemm1_body(const float* __restrict__ x,
                                  const ushort_t* __restrict__ w1t,
                                  ushort_t* __restrict__ h1,
                                  char* smem_, int row0, int tid) {
    ushort_t (*xs)[136] = (ushort_t (*)[136])smem_;
    const int wid = tid >> 6, lane = tid & 63;
    const int l15 = lane & 15, qq = lane >> 4;
    f32x4 acc[4];
#pragma unroll
    for (int i = 0; i < 4; ++i) acc[i] = (f32x4)0.f;
    for (int kc = 0; kc < 4; ++kc) {
        float4 f[8];
#pragma unroll
        for (int i = 0; i < 8; ++i) {
            int f4i = tid + 256 * i;
            int rr = f4i >> 5;
            int cc = f4i & 31;
            long gr = (long)min(row0 + rr, NN - 1);
            f[i] = *(const float4*)(x + gr * 512 + kc * 128 + cc * 4);
        }
        __syncthreads();
#pragma unroll
        for (int i = 0; i < 8; ++i) {
            int f4i = tid + 256 * i;
            int rr = f4i >> 5, cc = f4i & 31;
            uint2 uu;
            uu.x = ((unsigned)f2b(f[i].y) << 16) | f2b(f[i].x);
            uu.y = ((unsigned)f2b(f[i].w) << 16) | f2b(f[i].z);
            *(uint2*)&xs[rr][cc * 4] = uu;
        }
        __syncthreads();
#pragma unroll
        for (int ks = 0; ks < 4; ++ks) {
            short8 b = *(const short8*)(w1t + (size_t)(wid * 16 + l15) * 512 + kc * 128 + ks * 32 + qq * 8);
#pragma unroll
            for (int mt = 0; mt < 4; ++mt) {
                short8 a = *(const short8*)&xs[mt * 16 + l15][ks * 32 + qq * 8];
                acc[mt] = __builtin_amdgcn_mfma_f32_16x16x32_bf16(a, b, acc[mt], 0, 0, 0);
            }
        }
    }
#pragma unroll
    for (int mt = 0; mt < 4; ++mt) {
        int node = row0 + mt * 16 + qq * 4;
#pragma unroll
        for (int rr = 0; rr < 4; ++rr) {
            if (node + rr < NN)
                h1[(size_t)(node + rr) * 64 + wid * 16 + l15] = f2b(acc[mt][rr]);
        }
    }
}

// ---------------- fused: weight transpose (160) || coarse histogram (208) || q/p prep (1)
__global__ __launch_bounds__(256) void kfuse0(const float* __restrict__ W1,
                                              const float* __restrict__ W2,
                                              ushort_t* __restrict__ W1T,
                                              ushort_t* __restrict__ W2T,
                                              const int* __restrict__ ei,
                                              int* __restrict__ bbcnt,
                                              const float* __restrict__ aws2,
                                              const float* __restrict__ awd2,
                                              float* __restrict__ qp) {
    __shared__ int hist[NBK];
    const int t = threadIdx.x;
    if ((int)blockIdx.x < 160) {
        int tid = blockIdx.x * 256 + t;
        if (tid < 32768) {
            int k = tid >> 6, c = tid & 63;
            W1T[c * 512 + k] = f2b(W1[tid]);
        } else if (tid < 40960) {
            int q = tid - 32768;
            int k = q >> 7, c = q & 127;
            W2T[c * 64 + k] = f2b(W2[q]);
        }
    } else if ((int)blockIdx.x < 368) {
        const int blk = blockIdx.x - 160;
        for (int i = t; i < NBK; i += 256) hist[i] = 0;
        __syncthreads();
        const int e0 = blk * 8192;
#pragma unroll
        for (int i = 0; i < 32; ++i) {
            int e = e0 + t + 256 * i;
            if (e < ET) {
                int dst = (e < EE) ? ei[EE + e] : (e - EE);
                atomicAdd(&hist[dst >> 8], 1);
            }
        }
        __syncthreads();
        for (int i = t; i < NBK; i += 256) bbcnt[blk * NBK + i] = hist[i];
    } else {
        // qp[h*64+k] = sum_c W2[k][h*16+c]*aws2[h*16+c]; qp[512+...] same with awd2
        for (int e = t; e < 1024; e += 256) {
            int base = (e >= 512) ? (e - 512) : e;
            int h = base >> 6, k = base & 63;
            const float* w = (e >= 512) ? awd2 : aws2;
            float val = 0.f;
#pragma unroll
            for (int c = 0; c < 16; ++c) val += W2[k * 128 + h * 16 + c] * w[h * 16 + c];
            qp[e] = val;
        }
    }
}

// ---------------- in-place exclusive scan of bbcnt per bucket + bucket bases
__global__ __launch_bounds__(512) void kbscan(int* __restrict__ bbcnt,
                                              int* __restrict__ bbase) {
    __shared__ int tot[512];
    const int t = threadIdx.x;
    int total = 0;
    if (t < NBK) {
        int run = 0;
#pragma unroll 8
        for (int blk = 0; blk < NBLK; ++blk) {
            int idx = blk * NBK + t;
            int v = bbcnt[idx];
            bbcnt[idx] = run;
            run += v;
        }
        total = run;
    }
    tot[t] = total;
    __syncthreads();
    for (int off = 1; off < 512; off <<= 1) {
        int u = (t >= off) ? tot[t - off] : 0;
        __syncthreads();
        tot[t] += u;
        __syncthreads();
    }
    if (t < NBK) bbase[t] = tot[t] - total;  // exclusive
    if (t == 0) bbase[NBK] = ET;
}

// ---------------- fused: pair-binning scatter (208 blocks) || gemm1 first half (782 blocks)
__global__ __launch_bounds__(256) void kfuse1(const int* __restrict__ ei,
                                              const int* __restrict__ bbcnt,
                                              const int* __restrict__ bbase,
                                              unsigned* __restrict__ pairs,
                                              const float* __restrict__ x,
                                              const ushort_t* __restrict__ w1t,
                                              ushort_t* __restrict__ h1) {
    __shared__ __align__(16) char smem[17408];
    const int t = threadIdx.x;
    if ((int)blockIdx.x < NBLK) {
        int* cur = (int*)smem;
        const int blk = blockIdx.x;
        for (int i = t; i < NBK; i += 256) cur[i] = bbase[i] + bbcnt[blk * NBK + i];
        __syncthreads();
        const int e0 = blk * 8192;
#pragma unroll
        for (int i = 0; i < 32; ++i) {
            int e = e0 + t + 256 * i;
            if (e < ET) {
                int src, dst;
                if (e < EE) { src = ei[e]; dst = ei[EE + e]; } else { src = dst = e - EE; }
                int pos = atomicAdd(&cur[dst >> 8], 1);
                pairs[pos] = (unsigned)src | ((unsigned)(dst & 255) << 17);
            }
        }
    } else {
        gemm1_body(x, w1t, h1, smem, (blockIdx.x - NBLK) * 64, t);
    }
}

// ---------------- fused: per-bucket sort+rowp (391 blocks) || gemm1 second half (781 blocks)
__global__ __launch_bounds__(256) void kfuse2(const int* __restrict__ bbase,
                                              const unsigned* __restrict__ pairs,
                                              int* __restrict__ rowp,
                                              int* __restrict__ srt,
                                              const float* __restrict__ x,
                                              const ushort_t* __restrict__ w1t,
                                              ushort_t* __restrict__ h1) {
    __shared__ __align__(16) char smem[19456];
    const int t = threadIdx.x;
    if ((int)blockIdx.x < NBK) {
        int* hist = (int*)smem;
        int* scn = hist + 256;
        int* cur = scn + 256;
        unsigned* stage = (unsigned*)(smem + 3072);
        const int b = blockIdx.x;
        const int j0 = bbase[b], j1 = bbase[b + 1];
        const int cnt = j1 - j0;
        hist[t] = 0;
        __syncthreads();
        for (int i = t; i < cnt; i += 256) {
            unsigned p = pairs[j0 + i];
            if (i < STAGE_CAP) stage[i] = p;
            atomicAdd(&hist[p >> 17], 1);
        }
        __syncthreads();
        const int h = hist[t];
        scn[t] = h;
        __syncthreads();
        for (int off = 1; off < 256; off <<= 1) {
            int u = (t >= off) ? scn[t - off] : 0;
            __syncthreads();
            scn[t] += u;
            __syncthreads();
        }
        const int pref = scn[t] - h;  // exclusive prefix within bucket
        const int node = b * 256 + t;
        if (node < NN) rowp[node] = j0 + pref;
        if (b == 0 && t == 0) rowp[NN] = ET;
        cur[t] = pref;
        __syncthreads();
        for (int i = t; i < cnt; i += 256) {
            unsigned p = (i < STAGE_CAP) ? stage[i] : pairs[j0 + i];
            int l = (int)(p >> 17);
            int pos = atomicAdd(&cur[l], 1);
            srt[j0 + pos] = (int)(p & 0x1FFFFu);
        }
    } else {
        gemm1_body(x, w1t, h1, smem, (782 + (int)blockIdx.x - NBK) * 64, t);
    }
}

// ================= layer-1 fused agg: 2-way edge-split per (dst,head), inline alpha,
// pipelined gather. thread: node = tid>>4, head = (sub>>1), half = sub&1
__global__ __launch_bounds__(256) void kagg1(const int* __restrict__ rowp,
                                             const int* __restrict__ srt,
                                             const ushort_t* __restrict__ h1,
                                             const float* __restrict__ aws,
                                             const float* __restrict__ awd,
                                             const float* __restrict__ b1,
                                             const float* __restrict__ pw,
                                             ushort_t* __restrict__ hin) {
    int tid = blockIdx.x * 256 + threadIdx.x;  // exactly N*16
    int n = tid >> 4;
    int sub = tid & 15;
    int h = sub >> 1, half = sub & 1;
    float as_w[8], ad_w[8];
#pragma unroll
    for (int c = 0; c < 8; ++c) { as_w[c] = aws[h * 8 + c]; ad_w[c] = awd[h * 8 + c]; }
    uint4 hd = *(const uint4*)(h1 + (size_t)n * 64 + h * 8);
    const ushort_t* hdp = (const ushort_t*)&hd;
    float ad = 0.f;
#pragma unroll
    for (int c = 0; c < 8; ++c) ad += b2f(hdp[c]) * ad_w[c];
    int j0 = rowp[n], j1 = rowp[n + 1];
    float num[8]; float den = 0.f;
#pragma unroll
    for (int c = 0; c < 8; ++c) num[c] = 0.f;
    int j = j0 + half;
    uint4 hv;
    if (j < j1) {
        int s = srt[j];
        hv = *(const uint4*)(h1 + (size_t)s * 64 + h * 8);
    }
    while (j < j1) {
        int jn = j + 2;
        uint4 hn;
        if (jn < j1) {
            int sn = srt[jn];
            hn = *(const uint4*)(h1 + (size_t)sn * 64 + h * 8);
        }
        const ushort_t* hp = (const ushort_t*)&hv;
        float va[8];
#pragma unroll
        for (int c = 0; c < 8; ++c) va[c] = b2f(hp[c]);
        float sc = ad;
#pragma unroll
        for (int c = 0; c < 8; ++c) sc += va[c] * as_w[c];
        sc = (sc >= 0.f) ? sc : 0.2f * sc;
        float w = __expf(sc);
        den += w;
#pragma unroll
        for (int c = 0; c < 8; ++c) num[c] += w * va[c];
        j = jn;
        hv = hn;
    }
    // combine partner halves (lane^1)
#pragma unroll
    for (int c = 0; c < 8; ++c) num[c] += __shfl_xor(num[c], 1);
    den += __shfl_xor(den, 1);
    if (half == 0) {
        float inv = 1.f / den;  // den > 0 (self-loop guarantees >=1 edge)
        float pwf = pw[0];
        ushort_t o[8];
#pragma unroll
        for (int c = 0; c < 8; ++c) {
            float v = num[c] * inv + b1[h * 8 + c];
            v = (v >= 0.f) ? v : pwf * v;
            o[c] = f2b(v);
        }
        *(uint4*)(hin + (size_t)n * 64 + h * 8) = *(uint4*)o;
    }
}

// ---------------- dense layer-2 alphas from hin: as2/ad2[n][8] = hin[n]·q_h / hin[n]·p_h
__global__ __launch_bounds__(256) void kalpha2f(const ushort_t* __restrict__ hin,
                                                const float* __restrict__ qp,
                                                float* __restrict__ as2,
                                                float* __restrict__ ad2) {
    __shared__ float lq[1024];
    const int t = threadIdx.x;
    for (int i = t; i < 1024; i += 256) lq[i] = qp[i];
    __syncthreads();
    int gid = blockIdx.x * 256 + t;  // exactly N*8
    int n = gid >> 3, h = gid & 7;
    float s = 0.f, d = 0.f;
#pragma unroll
    for (int g = 0; g < 8; ++g) {
        uint4 v = *(const uint4*)(hin + (size_t)n * 64 + g * 8);
        const ushort_t* p = (const ushort_t*)&v;
        float4 qa = *(const float4*)&lq[h * 64 + g * 8];
        float4 qb = *(const float4*)&lq[h * 64 + g * 8 + 4];
        float4 pa = *(const float4*)&lq[512 + h * 64 + g * 8];
        float4 pb = *(const float4*)&lq[512 + h * 64 + g * 8 + 4];
        s += b2f(p[0]) * qa.x + b2f(p[1]) * qa.y + b2f(p[2]) * qa.z + b2f(p[3]) * qa.w;
        s += b2f(p[4]) * qb.x + b2f(p[5]) * qb.y + b2f(p[6]) * qb.z + b2f(p[7]) * qb.w;
        d += b2f(p[0]) * pa.x + b2f(p[1]) * pa.y + b2f(p[2]) * pa.z + b2f(p[3]) * pa.w;
        d += b2f(p[4]) * pb.x + b2f(p[5]) * pb.y + b2f(p[6]) * pb.z + b2f(p[7]) * pb.w;
    }
    as2[gid] = s;
    ad2[gid] = d;
}

// ================= layer-2 fused agg + deferred W2 (MFMA epilogue) + head-mean + log_softmax.
// Gathers hin rows (2 lines/edge) + as2 (1 shared line) instead of h2 (4 lines/edge).
// 16 threads/node = 8 heads x 2 channel-halves; both halves walk all edges.
__global__ __launch_bounds__(256) void kagg2f(const int* __restrict__ rowp,
                                              const int* __restrict__ srt,
                                              const ushort_t* __restrict__ hin,
                                              const float* __restrict__ as2,
                                              const float* __restrict__ ad2,
                                              const ushort_t* __restrict__ w2t,
                                              const float* __restrict__ b2,
                                              float* __restrict__ out) {
    __shared__ __align__(16) ushort_t agg[8 * AGG_HS];
    __shared__ float red[4][16][16];
    const int t = threadIdx.x;
    const int nl = t >> 4, sub = t & 15;
    const int h = sub >> 1, half = sub & 1;
    const int n = blockIdx.x * 16 + nl;
    const float ad = ad2[n * 8 + h];
    const int j0 = rowp[n], j1 = rowp[n + 1];
    float num[32];
#pragma unroll
    for (int c = 0; c < 32; ++c) num[c] = 0.f;
    float den = 0.f;
    // pipelined gather: deg >= 1 (self-loop)
    int j = j0;
    int s0 = srt[j];
    float as_ = as2[s0 * 8 + h];
    const ushort_t* rp = hin + (size_t)s0 * 64 + half * 32;
    uint4 r0 = *(const uint4*)(rp);
    uint4 r1 = *(const uint4*)(rp + 8);
    uint4 r2 = *(const uint4*)(rp + 16);
    uint4 r3 = *(const uint4*)(rp + 24);
    while (j < j1) {
        int jn = j + 1;
        uint4 n0, n1, n2, n3;
        float asn = 0.f;
        if (jn < j1) {
            int sn = srt[jn];
            asn = as2[sn * 8 + h];
            const ushort_t* np = hin + (size_t)sn * 64 + half * 32;
            n0 = *(const uint4*)(np);
            n1 = *(const uint4*)(np + 8);
            n2 = *(const uint4*)(np + 16);
            n3 = *(const uint4*)(np + 24);
        }
        float sc = as_ + ad;
        sc = (sc >= 0.f) ? sc : 0.2f * sc;
        float w = __expf(sc);
        den += w;
        {
            const ushort_t* p = (const ushort_t*)&r0;
#pragma unroll
            for (int c = 0; c < 8; ++c) num[c] += w * b2f(p[c]);
        }
        {
            const ushort_t* p = (const ushort_t*)&r1;
#pragma unroll
            for (int c = 0; c < 8; ++c) num[8 + c] += w * b2f(p[c]);
        }
        {
            const ushort_t* p = (const ushort_t*)&r2;
#pragma unroll
            for (int c = 0; c < 8; ++c) num[16 + c] += w * b2f(p[c]);
        }
        {
            const ushort_t* p = (const ushort_t*)&r3;
#pragma unroll
            for (int c = 0; c < 8; ++c) num[24 + c] += w * b2f(p[c]);
        }
        j = jn;
        r0 = n0; r1 = n1; r2 = n2; r3 = n3;
        as_ = asn;
    }
    // scale by per-head softmax denom and 1/8 head-mean; stage to LDS as bf16
    float g = 0.125f / den;
#pragma unroll
    for (int q = 0; q < 4; ++q) {
        ushort_t o[8];
#pragma unroll
        for (int c = 0; c < 8; ++c) o[c] = f2b(num[q * 8 + c] * g);
        *(uint4*)&agg[h * AGG_HS + nl * AGG_NS + half * 32 + q * 8] = *(uint4*)o;
    }
    __syncthreads();
    // deferred W2: out16[16n][16c] = sum_h agg[h] @ W2slice[h]; wave wid does heads {wid, wid+4}
    const int wid = t >> 6, lane = t & 63;
    const int l15 = lane & 15, qq = lane >> 4;
    f32x4 acc = (f32x4)0.f;
#pragma unroll
    for (int hh2 = 0; hh2 < 2; ++hh2) {
        int hh = wid + hh2 * 4;
#pragma unroll
        for (int ks = 0; ks < 2; ++ks) {
            short8 a = *(const short8*)&agg[hh * AGG_HS + l15 * AGG_NS + ks * 32 + qq * 8];
            short8 b = *(const short8*)(w2t + (size_t)(hh * 16 + l15) * 64 + ks * 32 + qq * 8);
            acc = __builtin_amdgcn_mfma_f32_16x16x32_bf16(a, b, acc, 0, 0, 0);
        }
    }
#pragma unroll
    for (int r = 0; r < 4; ++r) red[wid][qq * 4 + r][l15] = acc[r];
    __syncthreads();
    // cross-wave sum + bias + log_softmax (16 lanes per node), coalesced store
    {
        int c = sub;
        float v = red[0][nl][c] + red[1][nl][c] + red[2][nl][c] + red[3][nl][c] + b2[c];
        float m = v;
#pragma unroll
        for (int mask = 1; mask <= 8; mask <<= 1) m = fmaxf(m, __shfl_xor(m, mask));
        float e = __expf(v - m);
        float sum = e;
#pragma unroll
        for (int mask = 1; mask <= 8; mask <<= 1) sum += __shfl_xor(sum, mask);
        out[(size_t)n * 16 + c] = v - (__logf(sum) + m);
    }
}

extern "C" void kernel_launch(void* const* d_in, const int* in_sizes, int n_in,
                              void* d_out, int out_size, void* d_ws, size_t ws_size,
                              hipStream_t stream) {
    const float* x    = (const float*)d_in[0];
    const int*   ei   = (const int*)d_in[1];
    const float* W1   = (const float*)d_in[2];
    const float* aws1 = (const float*)d_in[3];
    const float* awd1 = (const float*)d_in[4];
    const float* b1   = (const float*)d_in[5];
    const float* pw   = (const float*)d_in[6];
    const float* W2   = (const float*)d_in[7];
    const float* aws2 = (const float*)d_in[8];
    const float* awd2 = (const float*)d_in[9];
    const float* b2   = (const float*)d_in[10];
    float* out = (float*)d_out;

    // Arena (46.5 MB peak):
    //   [ 0.0 -  6.8M) sorted_src (ET int)
    //   [ 6.8 -  7.2M) row_ptr (N+1 int)
    //   [ 7.2 -  7.53M) bbcnt table (NBLK x NBK int)
    //   [ 7.6M +1.6K ) bbase (NBK+1 int)
    //   [ 8.0 - 14.8M) pairs (ET u32)      [dead after kfuse2]
    //   [ 8.0 - 20.8M) hin (bf16)          [written by kagg1; read by kalpha2f/kagg2f]
    //   [20.8 - 33.6M) h1 (bf16)           [dead after kagg1]
    //   [20.8 - 24.0M) as2 (N*8 f32)       [over dead h1, written by kalpha2f]
    //   [24.0 - 27.2M) ad2 (N*8 f32)       [over dead h1]
    //   [46.4M+) W1T (64KB), W2T (16KB), qp (4KB)
    char* ws = (char*)d_ws;
    int*      srt   = (int*)(ws + 0);
    int*      rowp  = (int*)(ws + 6800000);
    int*      bbcnt = (int*)(ws + 7200256);
    int*      bbase = (int*)(ws + 7600384);
    unsigned* pairs = (unsigned*)(ws + 8000000);
    ushort_t* hin   = (ushort_t*)(ws + 8000000);
    ushort_t* h1    = (ushort_t*)(ws + 20800000);
    float*    as2   = (float*)(ws + 20800000);
    float*    ad2   = (float*)(ws + 24000000);
    ushort_t* W1T   = (ushort_t*)(ws + 46400000);
    ushort_t* W2T   = (ushort_t*)(ws + 46465536);
    float*    qp    = (float*)(ws + 46481920);

    kfuse0<<<369, 256, 0, stream>>>(W1, W2, W1T, W2T, ei, bbcnt, aws2, awd2, qp);
    kbscan<<<1, 512, 0, stream>>>(bbcnt, bbase);
    kfuse1<<<NBLK + 782, 256, 0, stream>>>(ei, bbcnt, bbase, pairs, x, W1T, h1);
    kfuse2<<<NBK + 781, 256, 0, stream>>>(bbase, pairs, rowp, srt, x, W1T, h1);
    kagg1<<<6250, 256, 0, stream>>>(rowp, srt, h1, aws1, awd1, b1, pw, hin);
    kalpha2f<<<3125, 256, 0, stream>>>(hin, qp, as2, ad2);
    kagg2f<<<6250, 256, 0, stream>>>(rowp, srt, hin, as2, ad2, W2T, b2, out);
}